// Round 15
// baseline (72.818 us; speedup 1.0000x reference)
//
#include <hip/hip_runtime.h>
#include <hip/hip_bf16.h>

// Problem constants
#define BDIM 1024
#define NCOL 1152      // 9 heads * 64 * 2 (q,k)
#define HEADS 9
#define HID 64
#define SLEN 512
#define BATCH 16

typedef __attribute__((ext_vector_type(8))) short bf16x8;
typedef __attribute__((ext_vector_type(8))) unsigned short u16x8;
typedef __attribute__((ext_vector_type(4))) float f32x4;
typedef __attribute__((ext_vector_type(4))) unsigned short u16x4;

static __device__ __forceinline__ unsigned short f2bf(float f) {
    union { float f; unsigned int u; } x; x.f = f;
    unsigned int u = x.u;
    unsigned int r = (u + 0x7fffu + ((u >> 16) & 1u)) >> 16;
    return (unsigned short)r;
}

#define GLOAD_LDS16(g, l)                                                     \
    __builtin_amdgcn_global_load_lds(                                         \
        (const __attribute__((address_space(1))) unsigned int*)(g),           \
        (__attribute__((address_space(3))) unsigned int*)(l), 16, 0, 0)

// ---------------------------------------------------------------------------
// Prep kernel (fused):
//   blocks [0,4096):     hidden f32 -> Ab bf16 (2048 elems/block)
//   blocks [4096,5248):  W [1024][1152] f32 -> Wt [1152][1024] bf16
//   blocks [5248,5312):  RoPE table sctab[512][32] of {sin,cos}
// ---------------------------------------------------------------------------
__global__ __launch_bounds__(256) void prep_kernel(const float* __restrict__ hidden,
                                                   const float* __restrict__ W,
                                                   unsigned short* __restrict__ Ab,
                                                   unsigned short* __restrict__ Wt,
                                                   float* __restrict__ sctab) {
    __shared__ float tile[32][33];
    const int b = blockIdx.x;
    if (b < 4096) {
        int i = (b * 256 + threadIdx.x) * 8;
        float4 a = *reinterpret_cast<const float4*>(hidden + i);
        float4 c = *reinterpret_cast<const float4*>(hidden + i + 4);
        u16x8 p;
        p[0] = f2bf(a.x); p[1] = f2bf(a.y); p[2] = f2bf(a.z); p[3] = f2bf(a.w);
        p[4] = f2bf(c.x); p[5] = f2bf(c.y); p[6] = f2bf(c.z); p[7] = f2bf(c.w);
        *reinterpret_cast<u16x8*>(Ab + i) = p;
    } else if (b < 5248) {
        const int bb = b - 4096;
        const int tx = threadIdx.x & 31;
        const int ty = threadIdx.x >> 5;      // 0..7
        const int nb = (bb % 36) * 32;        // over NCOL
        const int kb = (bb / 36) * 32;        // over BDIM
#pragma unroll
        for (int i = 0; i < 4; ++i) {
            int k = kb + ty + i * 8;
            tile[ty + i * 8][tx] = W[(size_t)k * NCOL + nb + tx];
        }
        __syncthreads();
#pragma unroll
        for (int i = 0; i < 4; ++i) {
            int n = nb + ty + i * 8;
            Wt[(size_t)n * BDIM + kb + tx] = f2bf(tile[tx][ty + i * 8]);
        }
    } else {
        int idx = (b - 5248) * 256 + threadIdx.x;   // 0..16383
        int s = idx >> 5, j = idx & 31;
        float inv = powf(10000.0f, -(float)(2 * j) / (float)HID);
        float ang = (float)s * inv;
        sctab[idx * 2]     = sinf(ang);
        sctab[idx * 2 + 1] = cosf(ang);
    }
}

// ---------------------------------------------------------------------------
// Projection GEMM (8192x1024 @ 1024x1152, both bf16) + bias + RoPE
// -> qk bf16 [16][9][2][512][64]
// R14 structure (best measured): BM=256 x BN=144, grid 32x8 = 256 blocks =
// 1/CU, 8 waves, BK=64, 3 LDS buffers, 2-deep counted-vmcnt prefetch,
// fused 36-MFMA setprio cluster, one barrier + one lgkm drain per iter.
// NEW: balanced B staging - w0-1 carry 3 B-gloads (rows 0-47), w2-7 carry 2
// (rows 48-143) -> per-SIMD load issue 13/13/12/12 (was 14/14/11/11).
// XOR-8 swizzle on 16B slots (source-side for gload_lds + swizzled ds_read).
// MFMA operand-swapped: acc regs run along the column (d) dimension.
// ---------------------------------------------------------------------------
__global__ __launch_bounds__(512) void proj_rope_kernel(
    const unsigned short* __restrict__ Ab,   // [8192][1024] bf16
    const unsigned short* __restrict__ Wt,   // [1152][1024] bf16
    const float* __restrict__ bias,          // [1152]
    const float4* __restrict__ sctab4,       // [512][16] {s,c,s,c}
    unsigned short* __restrict__ qk)         // [16][9][2][512][64] bf16
{
    __shared__ __attribute__((aligned(16))) unsigned short As[3][256 * 64]; // 96 KB
    __shared__ __attribute__((aligned(16))) unsigned short Bs[3][144 * 64]; // 54 KB

    const int t = threadIdx.x;
    const int m0 = blockIdx.x * 256;
    const int n0 = blockIdx.y * 144;
    const int wid = t >> 6, lane = t & 63;
    const int lrow = lane & 15;
    const int lk = lane >> 4;                 // 0..3

    const int rowoff = lane >> 3;                          // 0..7
    const int sslot = (lane & 7) ^ rowoff;                 // source 16B slot
    const unsigned short* gA = Ab + (size_t)(m0 + wid * 32 + rowoff) * BDIM + sslot * 8;
    // balanced B: w0-1 -> rows wid*24 (3 gloads); w2-7 -> 48+(wid-2)*16 (2)
    const int bbase = (wid < 2) ? wid * 24 : 48 + (wid - 2) * 16;
    const int bcnt  = (wid < 2) ? 3 : 2;
    const unsigned short* gB = Wt + (size_t)(n0 + bbase + rowoff) * BDIM + sslot * 8;
    const int lA = wid * 2048;                // elems: wave chunk in As
    const int lB = bbase * 64;                // elems: wave chunk in Bs

#define STAGE_A(buf, k0)                                                      \
    do {                                                                      \
        GLOAD_LDS16(gA + (k0),             &As[buf][lA]);                     \
        GLOAD_LDS16(gA + (k0) + 8 * BDIM,  &As[buf][lA + 512]);               \
        GLOAD_LDS16(gA + (k0) + 16 * BDIM, &As[buf][lA + 1024]);              \
        GLOAD_LDS16(gA + (k0) + 24 * BDIM, &As[buf][lA + 1536]);              \
    } while (0)
#define STAGE_B(buf, k0)                                                      \
    do {                                                                      \
        GLOAD_LDS16(gB + (k0),             &Bs[buf][lB]);                     \
        GLOAD_LDS16(gB + (k0) + 8 * BDIM,  &Bs[buf][lB + 512]);               \
        if (bcnt == 3)                                                        \
            GLOAD_LDS16(gB + (k0) + 16 * BDIM, &Bs[buf][lB + 1024]);          \
    } while (0)

    const int rkey = lrow & 7;

    f32x4 acc[9][2] = {};                     // [ni][mi], regs along n/d

    STAGE_A(0, 0);  STAGE_B(0, 0);
    STAGE_A(1, 64); STAGE_B(1, 64);

    int cur = 0;
    for (int it = 0; it < 16; ++it) {
        // counted wait: stage(it) complete, stage(it+1) stays in flight
        if (it < 15) {
            if (wid < 2) asm volatile("s_waitcnt vmcnt(7)" ::: "memory");
            else         asm volatile("s_waitcnt vmcnt(6)" ::: "memory");
        } else {
            asm volatile("s_waitcnt vmcnt(0)" ::: "memory");
        }
        __builtin_amdgcn_s_barrier();
        __builtin_amdgcn_sched_barrier(0);

        const char* Ac = (const char*)As[cur];
        const char* Bc = (const char*)Bs[cur];
        const int nb2 = (cur + 2 >= 3) ? cur - 1 : cur + 2;   // (it+2)%3

        // ---- fused phase: all frag reads (kk=0,1) + stage-issue + 36 MFMA
        bf16x8 af[2][2], bfr[2][9];
#pragma unroll
        for (int kk = 0; kk < 2; ++kk) {
            const int fslot = ((kk * 4 + lk) ^ rkey) << 4;
#pragma unroll
            for (int mi = 0; mi < 2; ++mi)
                af[kk][mi] = *reinterpret_cast<const bf16x8*>(
                    Ac + (wid * 32 + mi * 16 + lrow) * 128 + fslot);
#pragma unroll
            for (int ni = 0; ni < 9; ++ni)
                bfr[kk][ni] = *reinterpret_cast<const bf16x8*>(
                    Bc + (ni * 16 + lrow) * 128 + fslot);
        }
        if (it < 14) {
            STAGE_A(nb2, (it + 2) * 64);
            STAGE_B(nb2, (it + 2) * 64);
        }
        __builtin_amdgcn_sched_barrier(0);
        asm volatile("s_waitcnt lgkmcnt(0)" ::: "memory");
        __builtin_amdgcn_sched_barrier(0);
        __builtin_amdgcn_s_setprio(1);
#pragma unroll
        for (int kk = 0; kk < 2; ++kk)
#pragma unroll
            for (int ni = 0; ni < 9; ++ni)
#pragma unroll
                for (int mi = 0; mi < 2; ++mi)
                    acc[ni][mi] = __builtin_amdgcn_mfma_f32_16x16x32_bf16(
                        bfr[kk][ni], af[kk][mi], acc[ni][mi], 0, 0, 0);
        __builtin_amdgcn_s_setprio(0);

        cur = (cur + 1 >= 3) ? 0 : cur + 1;
    }
#undef STAGE_A
#undef STAGE_B

    // epilogue: bias + RoPE (in-register pairs) + ushort4 stores
    const float4* bias4 = (const float4*)bias;
#pragma unroll
    for (int ni = 0; ni < 9; ++ni) {
        int cb = n0 + ni * 16 + lk * 4;              // 4 consecutive columns
        float4 bv = bias4[cb >> 2];
        int h = cb >> 7;
        int qki = (cb >> 6) & 1;
        int d0 = cb & 63;                            // multiple of 4
#pragma unroll
        for (int mi = 0; mi < 2; ++mi) {
            int m = m0 + wid * 32 + mi * 16 + lrow;
            int bi = m >> 9, s = m & 511;
            float4 sc = sctab4[s * 16 + (d0 >> 2)];  // {sin j, cos j, sin j+1, cos j+1}
            f32x4 a = acc[ni][mi];
            float v0 = a[0] + bv.x, v1 = a[1] + bv.y;
            float v2 = a[2] + bv.z, v3 = a[3] + bv.w;
            u16x4 p;
            p[0] = f2bf(v0 * sc.y - v1 * sc.x);
            p[1] = f2bf(v1 * sc.y + v0 * sc.x);
            p[2] = f2bf(v2 * sc.w - v3 * sc.z);
            p[3] = f2bf(v3 * sc.w + v2 * sc.z);
            *reinterpret_cast<u16x4*>(
                qk + ((((size_t)bi * HEADS + h) * 2 + qki) * SLEN + s) * HID + d0) = p;
        }
    }
}

// ---------------------------------------------------------------------------
// logits[b,h,m,n] = (q.k * pad - (1-pad)*1e12) / 8
// per (b,h): 512x64 @ 64x512; grid (4,4,144), 128x128 tiles.
// MFMA operand-swapped. LDS-transposed epilogue (R11): per mi-chunk, waves
// write masked f32x4 into a [32][136] f32 tile, then 256 threads store
// contiguous 512B row-chunks (fully coalesced).
// ---------------------------------------------------------------------------
__global__ __launch_bounds__(256) void logits_kernel(
    const unsigned short* __restrict__ qkbuf,  // [16][9][2][512][64] bf16
    const float* __restrict__ mask,            // [16][512]
    float* __restrict__ out)                   // [16][9][512][512]
{
    __shared__ __attribute__((aligned(16))) unsigned short Qs[128 * 72];
    __shared__ __attribute__((aligned(16))) unsigned short Ks[128 * 72];

    const int t = threadIdx.x;
    const int bz = blockIdx.z;                 // b*9 + h
    const int bi = bz / 9;
    const int m0 = blockIdx.x * 128, n0 = blockIdx.y * 128;

    const unsigned short* Qg = qkbuf + ((size_t)bz * 2 + 0) * SLEN * HID + (size_t)m0 * HID;
    const unsigned short* Kg = qkbuf + ((size_t)bz * 2 + 1) * SLEN * HID + (size_t)n0 * HID;

#pragma unroll
    for (int i = 0; i < 4; ++i) {
        int e = t + i * 256;                   // 0..1023
        int row = e >> 3, c = e & 7;           // 8 x 16B per 64-elem row
        *reinterpret_cast<uint4*>(&Qs[row * 72 + c * 8]) =
            *reinterpret_cast<const uint4*>(Qg + (size_t)row * HID + c * 8);
        *reinterpret_cast<uint4*>(&Ks[row * 72 + c * 8]) =
            *reinterpret_cast<const uint4*>(Kg + (size_t)row * HID + c * 8);
    }
    __syncthreads();

    const int wid = t >> 6, lane = t & 63;
    const int wr = wid >> 1, wc = wid & 1;
    const int lrow = lane & 15;
    const int lk = lane >> 4;

    f32x4 acc[4][4] = {};                      // [ni][mi]
#pragma unroll
    for (int kk = 0; kk < 2; ++kk) {
        bf16x8 af[4], bfr[4];
#pragma unroll
        for (int mi = 0; mi < 4; ++mi)
            af[mi] = *reinterpret_cast<const bf16x8*>(
                &Qs[(wr * 64 + mi * 16 + lrow) * 72 + kk * 32 + lk * 8]);
#pragma unroll
        for (int ni = 0; ni < 4; ++ni)
            bfr[ni] = *reinterpret_cast<const bf16x8*>(
                &Ks[(wc * 64 + ni * 16 + lrow) * 72 + kk * 32 + lk * 8]);
#pragma unroll
        for (int ni = 0; ni < 4; ++ni)
#pragma unroll
            for (int mi = 0; mi < 4; ++mi)
                acc[ni][mi] = __builtin_amdgcn_mfma_f32_16x16x32_bf16(
                    bfr[ni], af[mi], acc[ni][mi], 0, 0, 0);
    }

    // mask factors per lane (depend only on n -> ni)
    float4 pv[4]; float4 sub[4];
#pragma unroll
    for (int ni = 0; ni < 4; ++ni) {
        int nb = n0 + wc * 64 + ni * 16 + lk * 4;
        pv[ni] = *reinterpret_cast<const float4*>(mask + bi * SLEN + nb);
        sub[ni].x = (1.0f - pv[ni].x) * 1000000000000.0f;
        sub[ni].y = (1.0f - pv[ni].y) * 1000000000000.0f;
        sub[ni].z = (1.0f - pv[ni].z) * 1000000000000.0f;
        sub[ni].w = (1.0f - pv[ni].w) * 1000000000000.0f;
    }

    // LDS-transposed store: chunk = 32 rows (wr bands) x 128 cols, pad 136
    float* tr = reinterpret_cast<float*>(Qs);   // 32*136*4 = 17408 B < 18432 B
    __syncthreads();                            // all Qs/Ks reads complete
#pragma unroll
    for (int mi = 0; mi < 4; ++mi) {
        if (mi) __syncthreads();                // prev chunk fully stored
#pragma unroll
        for (int ni = 0; ni < 4; ++ni) {
            int col = wc * 64 + ni * 16 + lk * 4;    // 0..127 within tile
            f32x4 a = acc[ni][mi];
            f32x4 o;
            o[0] = (a[0] * pv[ni].x - sub[ni].x) * 0.125f;
            o[1] = (a[1] * pv[ni].y - sub[ni].y) * 0.125f;
            o[2] = (a[2] * pv[ni].z - sub[ni].z) * 0.125f;
            o[3] = (a[3] * pv[ni].w - sub[ni].w) * 0.125f;
            *reinterpret_cast<f32x4*>(&tr[(wr * 16 + lrow) * 136 + col]) = o;
        }
        __syncthreads();
        // store 32 rows x 512B contiguous chunks, fully coalesced
#pragma unroll
        for (int j = 0; j < 4; ++j) {
            int idx = t + j * 256;               // 0..1023
            int r_l = idx >> 5, c4 = idx & 31;   // row 0..31, 16B col 0..31
            int m = m0 + (r_l >> 4) * 64 + mi * 16 + (r_l & 15);
            f32x4 v = *reinterpret_cast<const f32x4*>(&tr[r_l * 136 + c4 * 4]);
            *reinterpret_cast<f32x4*>(
                out + ((size_t)bz * SLEN + m) * SLEN + n0 + c4 * 4) = v;
        }
    }
}

// ---------------------------------------------------------------------------
extern "C" void kernel_launch(void* const* d_in, const int* in_sizes, int n_in,
                              void* d_out, int out_size, void* d_ws, size_t ws_size,
                              hipStream_t stream) {
    const float* hidden = (const float*)d_in[0];   // 16*512*1024
    const float* mask   = (const float*)d_in[1];   // 16*512
    const float* W      = (const float*)d_in[2];   // 1024*1152
    const float* bias   = (const float*)d_in[3];   // 1152
    float* out = (float*)d_out;

    char* ws = (char*)d_ws;
    unsigned short* Ab = (unsigned short*)ws;                        // 16,777,216 B
    unsigned short* Wt = (unsigned short*)(ws + 16777216);           //  2,359,296 B
    float* sctab = (float*)(ws + 16777216 + 2359296);                //    131,072 B
    unsigned short* qk = (unsigned short*)(ws + 16777216 + 2359296 + 131072); // 18,874,368 B

    prep_kernel<<<5312, 256, 0, stream>>>(hidden, W, Ab, Wt, sctab);
    proj_rope_kernel<<<dim3(32, 8), 512, 0, stream>>>(
        Ab, Wt, bias, (const float4*)sctab, qk);
    logits_kernel<<<dim3(4, 4, BATCH * HEADS), 256, 0, stream>>>(qk, mask, out);
}